// Round 1
// baseline (1188.503 us; speedup 1.0000x reference)
//
#include <hip/hip_runtime.h>
#include <math.h>

#define HD 128
#define AD 64

__device__ __forceinline__ float gelu_tanh(float v) {
    float v3 = v * v * v;
    float t = tanhf(0.7978845608028654f * (v + 0.044715f * v3));
    return 0.5f * v * (1.0f + t);
}

// ---------------- geometry: per-node mean rel offset + mean dist per scale ----
__global__ void geom_kernel(const float* __restrict__ coords,
                            const int* __restrict__ ip0, const int* __restrict__ ix0,
                            const int* __restrict__ ip1, const int* __restrict__ ix1,
                            float* __restrict__ geom, int n) {
    int i = blockIdx.x * blockDim.x + threadIdx.x;
    if (i >= n) return;
    float cx = coords[2 * i], cy = coords[2 * i + 1];
    #pragma unroll
    for (int s = 0; s < 2; ++s) {
        const int* ip = s ? ip1 : ip0;
        const int* ix = s ? ix1 : ix0;
        int st = ip[i], en = ip[i + 1];
        float sx = 0.f, sy = 0.f, sd = 0.f;
        for (int e = st; e < en; ++e) {
            int c = ix[e];
            float dx = coords[2 * c] - cx;
            float dy = coords[2 * c + 1] - cy;
            sx += dx; sy += dy;
            sd += sqrtf(dx * dx + dy * dy);
        }
        float inv = 1.0f / fmaxf((float)(en - st), 1.0f);
        geom[6 * i + 3 * s + 0] = sx * inv;
        geom[6 * i + 3 * s + 1] = sy * inv;
        geom[6 * i + 3 * s + 2] = sd * inv;
    }
}

// ---------------- prologue: x = gelu([fields|geom] @ W_in + b_in) -------------
__global__ void prologue_kernel(const float* __restrict__ fields,
                                const float* __restrict__ geom,
                                const float* __restrict__ W_in,
                                const float* __restrict__ b_in,
                                float* __restrict__ x, int n) {
    int node = blockIdx.x * 2 + (threadIdx.x >> 7);
    int col = threadIdx.x & 127;
    if (node >= n) return;
    float acc = b_in[col];
    const float* f = fields + (size_t)node * 16;
    const float* g = geom + (size_t)node * 6;
    #pragma unroll
    for (int k = 0; k < 16; ++k) acc += f[k] * W_in[k * HD + col];
    #pragma unroll
    for (int k = 0; k < 6; ++k) acc += g[k] * W_in[(16 + k) * HD + col];
    x[(size_t)node * HD + col] = gelu_tanh(acc);
}

// ---------------- QKV GEMM: out[N,256] = X[N,128] @ [Wq|Wk|Wv], q/k row-normed
__global__ __launch_bounds__(256, 2)
void qkv_gemm_kernel(const float* __restrict__ X,
                     const float* __restrict__ Wq,   // [128,64]
                     const float* __restrict__ Wk,   // [128,64]
                     const float* __restrict__ Wv,   // [128,128]
                     float* __restrict__ out, int n) {
    __shared__ float Xs[64][36];      // +4 pad: bank spread, keeps 16B align
    __shared__ float Ws[32][256];
    int t = threadIdx.x;
    int tx = t & 15, ty = t >> 4;
    int m0 = blockIdx.x * 64;
    float4 acc[4][4];
    #pragma unroll
    for (int i = 0; i < 4; ++i)
        #pragma unroll
        for (int g = 0; g < 4; ++g) acc[i][g] = make_float4(0.f, 0.f, 0.f, 0.f);

    for (int kc = 0; kc < 128; kc += 32) {
        #pragma unroll
        for (int it = 0; it < 2; ++it) {            // X tile: 512 float4
            int idx = t + it * 256;
            int row = idx >> 3, k4 = idx & 7;
            float4 v = make_float4(0.f, 0.f, 0.f, 0.f);
            if (m0 + row < n)
                v = *(const float4*)&X[(size_t)(m0 + row) * 128 + kc + k4 * 4];
            *(float4*)&Xs[row][k4 * 4] = v;
        }
        #pragma unroll
        for (int it = 0; it < 8; ++it) {            // W tile: 2048 float4
            int idx = t + it * 256;
            int k = idx >> 6, c4 = idx & 63;
            int col = c4 * 4;
            const float* src;
            if (col < 64)       src = Wq + (size_t)(kc + k) * 64 + col;
            else if (col < 128) src = Wk + (size_t)(kc + k) * 64 + (col - 64);
            else                src = Wv + (size_t)(kc + k) * 128 + (col - 128);
            *(float4*)&Ws[k][col] = *(const float4*)src;
        }
        __syncthreads();
        #pragma unroll
        for (int k4 = 0; k4 < 8; ++k4) {
            float4 xr[4];
            #pragma unroll
            for (int i = 0; i < 4; ++i)
                xr[i] = *(float4*)&Xs[ty + 16 * i][k4 * 4];
            #pragma unroll
            for (int kk = 0; kk < 4; ++kk) {
                #pragma unroll
                for (int g = 0; g < 4; ++g) {
                    float4 w = *(float4*)&Ws[k4 * 4 + kk][g * 64 + tx * 4];
                    #pragma unroll
                    for (int i = 0; i < 4; ++i) {
                        float xv = (&xr[i].x)[kk];
                        acc[i][g].x += xv * w.x;
                        acc[i][g].y += xv * w.y;
                        acc[i][g].z += xv * w.z;
                        acc[i][g].w += xv * w.w;
                    }
                }
            }
        }
        __syncthreads();
    }
    // epilogue: cosine-normalize q (group 0) and k (group 1) per row
    #pragma unroll
    for (int i = 0; i < 4; ++i) {
        #pragma unroll
        for (int g = 0; g < 2; ++g) {
            float4 a = acc[i][g];
            float sq = a.x * a.x + a.y * a.y + a.z * a.z + a.w * a.w;
            #pragma unroll
            for (int m = 1; m < 16; m <<= 1) sq += __shfl_xor(sq, m, 64);
            float f = 1.0f / (sqrtf(sq) + 1e-6f);
            acc[i][g].x *= f; acc[i][g].y *= f; acc[i][g].z *= f; acc[i][g].w *= f;
        }
    }
    #pragma unroll
    for (int i = 0; i < 4; ++i) {
        int row = m0 + ty + 16 * i;
        if (row < n) {
            #pragma unroll
            for (int g = 0; g < 4; ++g)
                *(float4*)&out[(size_t)row * 256 + g * 64 + tx * 4] = acc[i][g];
        }
    }
}

// ---------------- attention per scale: one wave per node ----------------------
__global__ void attn_kernel(const float* __restrict__ qkv,   // [N,256] qn|kn|v
                            const int* __restrict__ indptr,
                            const int* __restrict__ indices,
                            float* __restrict__ agg,         // [N,256]
                            int scale, int n) {
    int wid = threadIdx.x >> 6;
    int lane = threadIdx.x & 63;
    int i = blockIdx.x * (blockDim.x >> 6) + wid;
    if (i >= n) return;
    int half = lane >> 5;         // edge parity within pair
    int hl = lane & 31;           // q/k dim pair index
    float2 q2 = *(const float2*)&qkv[(size_t)i * 256 + 2 * hl];
    int st = indptr[i];
    int deg = indptr[i + 1] - st;
    int nd = deg > 16 ? 16 : deg;     // degrees are 12 / 4 by construction
    float scores[16];
    for (int e0 = 0; e0 < nd; e0 += 2) {
        int e = e0 + half;
        int c = indices[st + ((e < nd) ? e : e0)];
        float2 k2 = *(const float2*)&qkv[(size_t)c * 256 + 64 + 2 * hl];
        float p = q2.x * k2.x + q2.y * k2.y;
        #pragma unroll
        for (int m = 1; m < 32; m <<= 1) p += __shfl_xor(p, m, 64);
        float s0 = __shfl(p, 0, 64);
        float s1 = __shfl(p, 32, 64);
        scores[e0] = s0;
        if (e0 + 1 < nd) scores[e0 + 1] = s1;
    }
    float mx = -INFINITY;
    for (int e = 0; e < nd; ++e) mx = fmaxf(mx, scores[e]);
    float den = 0.f;
    for (int e = 0; e < nd; ++e) { scores[e] = expf(scores[e] - mx); den += scores[e]; }
    float inv = (den > 0.f) ? 1.0f / den : 0.f;
    float2 a = make_float2(0.f, 0.f);
    for (int e = 0; e < nd; ++e) {
        int c = indices[st + e];                       // broadcast load
        float al = scores[e] * inv;
        float2 v2 = *(const float2*)&qkv[(size_t)c * 256 + 128 + 2 * lane];
        a.x += al * v2.x;
        a.y += al * v2.y;
    }
    *(float2*)&agg[(size_t)i * 256 + scale * 128 + 2 * lane] = a;
}

// ---------------- Wo GEMM: x += gelu(agg[N,256] @ Wo + bo) --------------------
__global__ __launch_bounds__(256, 2)
void wo_gemm_kernel(const float* __restrict__ agg,
                    const float* __restrict__ Wo,    // [256,128]
                    const float* __restrict__ bo,    // [128]
                    float* __restrict__ x, int n) {
    __shared__ float Xs[64][36];
    __shared__ float Ws[32][128];
    int t = threadIdx.x;
    int tx = t & 15, ty = t >> 4;
    int m0 = blockIdx.x * 64;
    float4 acc[4][2];
    #pragma unroll
    for (int i = 0; i < 4; ++i)
        #pragma unroll
        for (int g = 0; g < 2; ++g) acc[i][g] = make_float4(0.f, 0.f, 0.f, 0.f);

    for (int kc = 0; kc < 256; kc += 32) {
        #pragma unroll
        for (int it = 0; it < 2; ++it) {
            int idx = t + it * 256;
            int row = idx >> 3, k4 = idx & 7;
            float4 v = make_float4(0.f, 0.f, 0.f, 0.f);
            if (m0 + row < n)
                v = *(const float4*)&agg[(size_t)(m0 + row) * 256 + kc + k4 * 4];
            *(float4*)&Xs[row][k4 * 4] = v;
        }
        #pragma unroll
        for (int it = 0; it < 4; ++it) {
            int idx = t + it * 256;
            int k = idx >> 5, c4 = idx & 31;
            *(float4*)&Ws[k][c4 * 4] = *(const float4*)&Wo[(size_t)(kc + k) * 128 + c4 * 4];
        }
        __syncthreads();
        #pragma unroll
        for (int k4 = 0; k4 < 8; ++k4) {
            float4 xr[4];
            #pragma unroll
            for (int i = 0; i < 4; ++i)
                xr[i] = *(float4*)&Xs[ty + 16 * i][k4 * 4];
            #pragma unroll
            for (int kk = 0; kk < 4; ++kk) {
                #pragma unroll
                for (int g = 0; g < 2; ++g) {
                    float4 w = *(float4*)&Ws[k4 * 4 + kk][g * 64 + tx * 4];
                    #pragma unroll
                    for (int i = 0; i < 4; ++i) {
                        float xv = (&xr[i].x)[kk];
                        acc[i][g].x += xv * w.x;
                        acc[i][g].y += xv * w.y;
                        acc[i][g].z += xv * w.z;
                        acc[i][g].w += xv * w.w;
                    }
                }
            }
        }
        __syncthreads();
    }
    #pragma unroll
    for (int i = 0; i < 4; ++i) {
        int row = m0 + ty + 16 * i;
        if (row < n) {
            #pragma unroll
            for (int g = 0; g < 2; ++g) {
                float4 a = acc[i][g];
                float4 b = *(const float4*)&bo[g * 64 + tx * 4];
                float4 xv = *(const float4*)&x[(size_t)row * 128 + g * 64 + tx * 4];
                float4 r;
                r.x = xv.x + gelu_tanh(a.x + b.x);
                r.y = xv.y + gelu_tanh(a.y + b.y);
                r.z = xv.z + gelu_tanh(a.z + b.z);
                r.w = xv.w + gelu_tanh(a.w + b.w);
                *(float4*)&x[(size_t)row * 128 + g * 64 + tx * 4] = r;
            }
        }
    }
}

extern "C" void kernel_launch(void* const* d_in, const int* in_sizes, int n_in,
                              void* d_out, int out_size, void* d_ws, size_t ws_size,
                              hipStream_t stream) {
    const float* coords = (const float*)d_in[0];
    const float* fields = (const float*)d_in[1];
    const int*   ip0    = (const int*)d_in[2];
    const int*   ix0    = (const int*)d_in[3];
    const int*   ip1    = (const int*)d_in[4];
    const int*   ix1    = (const int*)d_in[5];
    const float* W_in   = (const float*)d_in[6];
    const float* b_in   = (const float*)d_in[7];
    const float* Wq     = (const float*)d_in[8];
    const float* Wk     = (const float*)d_in[9];
    const float* Wv     = (const float*)d_in[10];
    const float* Wo     = (const float*)d_in[11];
    const float* bo     = (const float*)d_in[12];

    int n = in_sizes[0] / 2;          // coords is [N,2]
    float* x = (float*)d_out;         // x lives in d_out throughout

    char* ws = (char*)d_ws;
    size_t geom_bytes = ((size_t)n * 6 * 4 + 255) & ~(size_t)255;
    float* geom = (float*)ws;
    float* qkv  = (float*)(ws + geom_bytes);
    float* agg  = qkv + (size_t)n * 256;

    geom_kernel<<<(n + 255) / 256, 256, 0, stream>>>(coords, ip0, ix0, ip1, ix1, geom, n);
    prologue_kernel<<<(n + 1) / 2, 256, 0, stream>>>(fields, geom, W_in, b_in, x, n);

    int gblocks = (n + 63) / 64;
    int ablocks = (n + 3) / 4;
    for (int l = 0; l < 3; ++l) {
        for (int s = 0; s < 2; ++s) {
            const float* wq = Wq + (size_t)(l * 2 + s) * 128 * 64;
            const float* wk = Wk + (size_t)(l * 2 + s) * 128 * 64;
            const float* wv = Wv + (size_t)(l * 2 + s) * 128 * 128;
            qkv_gemm_kernel<<<gblocks, 256, 0, stream>>>(x, wq, wk, wv, qkv, n);
            attn_kernel<<<ablocks, 256, 0, stream>>>(qkv, s ? ip1 : ip0, s ? ix1 : ix0,
                                                     agg, s, n);
        }
        wo_gemm_kernel<<<gblocks, 256, 0, stream>>>(agg, Wo + (size_t)l * 256 * 128,
                                                    bo + l * 128, x, n);
    }
}

// Round 3
// 1002.947 us; speedup vs baseline: 1.1850x; 1.1850x over previous
//
#include <hip/hip_runtime.h>
#include <hip/hip_fp16.h>
#include <math.h>

#define HD 128
#define AD 64

__device__ __forceinline__ float gelu_tanh(float v) {
    float v3 = v * v * v;
    float t = tanhf(0.7978845608028654f * (v + 0.044715f * v3));
    return 0.5f * v * (1.0f + t);
}

__device__ __forceinline__ void store_h4(__half* p, float4 a) {
    __half2 lo = __float22half2_rn(make_float2(a.x, a.y));
    __half2 hi = __float22half2_rn(make_float2(a.z, a.w));
    uint2 u;
    u.x = *(unsigned*)&lo;
    u.y = *(unsigned*)&hi;
    *(uint2*)p = u;
}

__device__ __forceinline__ float4 load_h4(const __half* p) {
    uint2 raw = *(const uint2*)p;
    float2 lo = __half22float2(*(__half2*)&raw.x);
    float2 hi = __half22float2(*(__half2*)&raw.y);
    return make_float4(lo.x, lo.y, hi.x, hi.y);
}

// ---------------- geometry: per-node mean rel offset + mean dist per scale ----
__global__ void geom_kernel(const float* __restrict__ coords,
                            const int* __restrict__ ip0, const int* __restrict__ ix0,
                            const int* __restrict__ ip1, const int* __restrict__ ix1,
                            float* __restrict__ geom, int n) {
    int i = blockIdx.x * blockDim.x + threadIdx.x;
    if (i >= n) return;
    float cx = coords[2 * i], cy = coords[2 * i + 1];
    #pragma unroll
    for (int s = 0; s < 2; ++s) {
        const int* ip = s ? ip1 : ip0;
        const int* ix = s ? ix1 : ix0;
        int st = ip[i], en = ip[i + 1];
        float sx = 0.f, sy = 0.f, sd = 0.f;
        for (int e = st; e < en; ++e) {
            int c = ix[e];
            float dx = coords[2 * c] - cx;
            float dy = coords[2 * c + 1] - cy;
            sx += dx; sy += dy;
            sd += sqrtf(dx * dx + dy * dy);
        }
        float inv = 1.0f / fmaxf((float)(en - st), 1.0f);
        geom[6 * i + 3 * s + 0] = sx * inv;
        geom[6 * i + 3 * s + 1] = sy * inv;
        geom[6 * i + 3 * s + 2] = sd * inv;
    }
}

// ---------------- prologue: x = gelu([fields|geom] @ W_in + b_in) -------------
__global__ void prologue_kernel(const float* __restrict__ fields,
                                const float* __restrict__ geom,
                                const float* __restrict__ W_in,
                                const float* __restrict__ b_in,
                                float* __restrict__ x, int n) {
    int node = blockIdx.x * 2 + (threadIdx.x >> 7);
    int col = threadIdx.x & 127;
    if (node >= n) return;
    float acc = b_in[col];
    const float* f = fields + (size_t)node * 16;
    const float* g = geom + (size_t)node * 6;
    #pragma unroll
    for (int k = 0; k < 16; ++k) acc += f[k] * W_in[k * HD + col];
    #pragma unroll
    for (int k = 0; k < 6; ++k) acc += g[k] * W_in[(16 + k) * HD + col];
    x[(size_t)node * HD + col] = gelu_tanh(acc);
}

// ---------------- QKV GEMM: q/k row-normalized, outputs stored fp16 -----------
__global__ __launch_bounds__(256, 2)
void qkv_gemm_kernel(const float* __restrict__ X,
                     const float* __restrict__ Wq,   // [128,64]
                     const float* __restrict__ Wk,   // [128,64]
                     const float* __restrict__ Wv,   // [128,128]
                     __half* __restrict__ qh,        // [N,64]
                     __half* __restrict__ kh,        // [N,64]
                     __half* __restrict__ vh,        // [N,128]
                     int n) {
    __shared__ float Xs[64][36];
    __shared__ float Ws[32][256];
    int t = threadIdx.x;
    int tx = t & 15, ty = t >> 4;
    int m0 = blockIdx.x * 64;
    float4 acc[4][4];
    #pragma unroll
    for (int i = 0; i < 4; ++i)
        #pragma unroll
        for (int g = 0; g < 4; ++g) acc[i][g] = make_float4(0.f, 0.f, 0.f, 0.f);

    for (int kc = 0; kc < 128; kc += 32) {
        #pragma unroll
        for (int it = 0; it < 2; ++it) {
            int idx = t + it * 256;
            int row = idx >> 3, k4 = idx & 7;
            float4 v = make_float4(0.f, 0.f, 0.f, 0.f);
            if (m0 + row < n)
                v = *(const float4*)&X[(size_t)(m0 + row) * 128 + kc + k4 * 4];
            *(float4*)&Xs[row][k4 * 4] = v;
        }
        #pragma unroll
        for (int it = 0; it < 8; ++it) {
            int idx = t + it * 256;
            int k = idx >> 6, c4 = idx & 63;
            int col = c4 * 4;
            const float* src;
            if (col < 64)       src = Wq + (size_t)(kc + k) * 64 + col;
            else if (col < 128) src = Wk + (size_t)(kc + k) * 64 + (col - 64);
            else                src = Wv + (size_t)(kc + k) * 128 + (col - 128);
            *(float4*)&Ws[k][col] = *(const float4*)src;
        }
        __syncthreads();
        #pragma unroll
        for (int k4 = 0; k4 < 8; ++k4) {
            float4 xr[4];
            #pragma unroll
            for (int i = 0; i < 4; ++i)
                xr[i] = *(float4*)&Xs[ty + 16 * i][k4 * 4];
            #pragma unroll
            for (int kk = 0; kk < 4; ++kk) {
                #pragma unroll
                for (int g = 0; g < 4; ++g) {
                    float4 w = *(float4*)&Ws[k4 * 4 + kk][g * 64 + tx * 4];
                    #pragma unroll
                    for (int i = 0; i < 4; ++i) {
                        float xv = (&xr[i].x)[kk];
                        acc[i][g].x += xv * w.x;
                        acc[i][g].y += xv * w.y;
                        acc[i][g].z += xv * w.z;
                        acc[i][g].w += xv * w.w;
                    }
                }
            }
        }
        __syncthreads();
    }
    // epilogue: cosine-normalize q (group 0) and k (group 1) per row
    #pragma unroll
    for (int i = 0; i < 4; ++i) {
        #pragma unroll
        for (int g = 0; g < 2; ++g) {
            float4 a = acc[i][g];
            float sq = a.x * a.x + a.y * a.y + a.z * a.z + a.w * a.w;
            #pragma unroll
            for (int m = 1; m < 16; m <<= 1) sq += __shfl_xor(sq, m, 64);
            float f = 1.0f / (sqrtf(sq) + 1e-6f);
            acc[i][g].x *= f; acc[i][g].y *= f; acc[i][g].z *= f; acc[i][g].w *= f;
        }
    }
    #pragma unroll
    for (int i = 0; i < 4; ++i) {
        int row = m0 + ty + 16 * i;
        if (row < n) {
            store_h4(&qh[(size_t)row * 64 + tx * 4], acc[i][0]);
            store_h4(&kh[(size_t)row * 64 + tx * 4], acc[i][1]);
            store_h4(&vh[(size_t)row * 128 + tx * 4], acc[i][2]);
            store_h4(&vh[(size_t)row * 128 + 64 + tx * 4], acc[i][3]);
        }
    }
}

// ---------------- attention: one wave per node, degree templated --------------
// score phase: 16 lanes per edge (4 edges in flight), half4 loads
// v phase:     32 lanes per edge (2 edges in flight), half4 loads
template<int DEG>
__global__ void attn_kernel_t(const __half* __restrict__ qh,
                              const __half* __restrict__ kh,
                              const __half* __restrict__ vh,
                              const int* __restrict__ indptr,
                              const int* __restrict__ indices,
                              float* __restrict__ agg,     // [N,256]
                              int scale, int n) {
    int wid = threadIdx.x >> 6;
    int lane = threadIdx.x & 63;
    int i = blockIdx.x * (blockDim.x >> 6) + wid;
    if (i >= n) return;
    int g = lane >> 4, sl = lane & 15;
    int st = indptr[i];

    float4 q = load_h4(&qh[(size_t)i * 64 + sl * 4]);

    float sc[DEG];
    constexpr int NIT = (DEG + 3) / 4;
    #pragma unroll
    for (int it = 0; it < NIT; ++it) {
        int e = it * 4 + g;
        int ee = (e < DEG) ? e : (DEG - 1);
        int c = indices[st + ee];
        float4 k = load_h4(&kh[(size_t)c * 64 + sl * 4]);
        float p = q.x * k.x + q.y * k.y + q.z * k.z + q.w * k.w;
        p += __shfl_xor(p, 1, 64);
        p += __shfl_xor(p, 2, 64);
        p += __shfl_xor(p, 4, 64);
        p += __shfl_xor(p, 8, 64);
        #pragma unroll
        for (int j = 0; j < 4; ++j) {
            int e2 = it * 4 + j;
            if (e2 < DEG) sc[e2] = __shfl(p, j * 16, 64);
        }
    }

    float mx = sc[0];
    #pragma unroll
    for (int e = 1; e < DEG; ++e) mx = fmaxf(mx, sc[e]);
    float den = 0.f;
    #pragma unroll
    for (int e = 0; e < DEG; ++e) { sc[e] = __expf(sc[e] - mx); den += sc[e]; }
    float inv = 1.0f / den;

    int half = lane >> 5, hl = lane & 31;
    float4 a = make_float4(0.f, 0.f, 0.f, 0.f);
    #pragma unroll
    for (int it = 0; it < DEG / 2; ++it) {
        int c = indices[st + 2 * it + half];
        float al = (half ? sc[2 * it + 1] : sc[2 * it]) * inv;
        float4 v = load_h4(&vh[(size_t)c * 128 + hl * 4]);
        a.x += al * v.x; a.y += al * v.y; a.z += al * v.z; a.w += al * v.w;
    }
    a.x += __shfl_xor(a.x, 32, 64);
    a.y += __shfl_xor(a.y, 32, 64);
    a.z += __shfl_xor(a.z, 32, 64);
    a.w += __shfl_xor(a.w, 32, 64);
    if (half == 0)
        *(float4*)&agg[(size_t)i * 256 + scale * 128 + hl * 4] = a;
}

// generic fallback (any degree up to 32) — correctness net only
__global__ void attn_generic(const __half* __restrict__ qh,
                             const __half* __restrict__ kh,
                             const __half* __restrict__ vh,
                             const int* __restrict__ indptr,
                             const int* __restrict__ indices,
                             float* __restrict__ agg, int scale, int n) {
    int wid = threadIdx.x >> 6;
    int lane = threadIdx.x & 63;
    int i = blockIdx.x * (blockDim.x >> 6) + wid;
    if (i >= n) return;
    int g = lane >> 4, sl = lane & 15;
    int st = indptr[i];
    int deg = indptr[i + 1] - st;
    if (deg > 32) deg = 32;
    if (deg <= 0) {
        if (lane < 32)
            *(float4*)&agg[(size_t)i * 256 + scale * 128 + (lane & 31) * 4] =
                make_float4(0.f, 0.f, 0.f, 0.f);
        return;
    }
    float4 q = load_h4(&qh[(size_t)i * 64 + sl * 4]);
    float sc[32];
    for (int e0 = 0; e0 < deg; e0 += 4) {
        int e = e0 + g;
        int ee = (e < deg) ? e : (deg - 1);
        int c = indices[st + ee];
        float4 k = load_h4(&kh[(size_t)c * 64 + sl * 4]);
        float p = q.x * k.x + q.y * k.y + q.z * k.z + q.w * k.w;
        p += __shfl_xor(p, 1, 64);
        p += __shfl_xor(p, 2, 64);
        p += __shfl_xor(p, 4, 64);
        p += __shfl_xor(p, 8, 64);
        for (int j = 0; j < 4; ++j)
            if (e0 + j < deg) sc[e0 + j] = __shfl(p, j * 16, 64);
    }
    float mx = -INFINITY;
    for (int e = 0; e < deg; ++e) mx = fmaxf(mx, sc[e]);
    float den = 0.f;
    for (int e = 0; e < deg; ++e) { sc[e] = __expf(sc[e] - mx); den += sc[e]; }
    float inv = 1.0f / den;
    int half = lane >> 5, hl = lane & 31;
    float4 a = make_float4(0.f, 0.f, 0.f, 0.f);
    for (int e0 = 0; e0 < deg; e0 += 2) {
        int e = e0 + half;
        if (e < deg) {
            int c = indices[st + e];
            float al = sc[e] * inv;
            float4 v = load_h4(&vh[(size_t)c * 128 + hl * 4]);
            a.x += al * v.x; a.y += al * v.y; a.z += al * v.z; a.w += al * v.w;
        }
    }
    a.x += __shfl_xor(a.x, 32, 64);
    a.y += __shfl_xor(a.y, 32, 64);
    a.z += __shfl_xor(a.z, 32, 64);
    a.w += __shfl_xor(a.w, 32, 64);
    if (half == 0)
        *(float4*)&agg[(size_t)i * 256 + scale * 128 + hl * 4] = a;
}

// ---------------- Wo GEMM: x += gelu(agg[N,256] @ Wo + bo) --------------------
__global__ __launch_bounds__(256, 2)
void wo_gemm_kernel(const float* __restrict__ agg,
                    const float* __restrict__ Wo,    // [256,128]
                    const float* __restrict__ bo,    // [128]
                    float* __restrict__ x, int n) {
    __shared__ float Xs[64][36];
    __shared__ float Ws[32][128];
    int t = threadIdx.x;
    int tx = t & 15, ty = t >> 4;
    int m0 = blockIdx.x * 64;
    float4 acc[4][2];
    #pragma unroll
    for (int i = 0; i < 4; ++i)
        #pragma unroll
        for (int g = 0; g < 2; ++g) acc[i][g] = make_float4(0.f, 0.f, 0.f, 0.f);

    for (int kc = 0; kc < 256; kc += 32) {
        #pragma unroll
        for (int it = 0; it < 2; ++it) {
            int idx = t + it * 256;
            int row = idx >> 3, k4 = idx & 7;
            float4 v = make_float4(0.f, 0.f, 0.f, 0.f);
            if (m0 + row < n)
                v = *(const float4*)&agg[(size_t)(m0 + row) * 256 + kc + k4 * 4];
            *(float4*)&Xs[row][k4 * 4] = v;
        }
        #pragma unroll
        for (int it = 0; it < 4; ++it) {
            int idx = t + it * 256;
            int k = idx >> 5, c4 = idx & 31;
            *(float4*)&Ws[k][c4 * 4] = *(const float4*)&Wo[(size_t)(kc + k) * 128 + c4 * 4];
        }
        __syncthreads();
        #pragma unroll
        for (int k4 = 0; k4 < 8; ++k4) {
            float4 xr[4];
            #pragma unroll
            for (int i = 0; i < 4; ++i)
                xr[i] = *(float4*)&Xs[ty + 16 * i][k4 * 4];
            #pragma unroll
            for (int kk = 0; kk < 4; ++kk) {
                #pragma unroll
                for (int g = 0; g < 2; ++g) {
                    float4 w = *(float4*)&Ws[k4 * 4 + kk][g * 64 + tx * 4];
                    #pragma unroll
                    for (int i = 0; i < 4; ++i) {
                        float xv = (&xr[i].x)[kk];
                        acc[i][g].x += xv * w.x;
                        acc[i][g].y += xv * w.y;
                        acc[i][g].z += xv * w.z;
                        acc[i][g].w += xv * w.w;
                    }
                }
            }
        }
        __syncthreads();
    }
    #pragma unroll
    for (int i = 0; i < 4; ++i) {
        int row = m0 + ty + 16 * i;
        if (row < n) {
            #pragma unroll
            for (int g = 0; g < 2; ++g) {
                float4 a = acc[i][g];
                float4 b = *(const float4*)&bo[g * 64 + tx * 4];
                float4 xv = *(const float4*)&x[(size_t)row * 128 + g * 64 + tx * 4];
                float4 r;
                r.x = xv.x + gelu_tanh(a.x + b.x);
                r.y = xv.y + gelu_tanh(a.y + b.y);
                r.z = xv.z + gelu_tanh(a.z + b.z);
                r.w = xv.w + gelu_tanh(a.w + b.w);
                *(float4*)&x[(size_t)row * 128 + g * 64 + tx * 4] = r;
            }
        }
    }
}

extern "C" void kernel_launch(void* const* d_in, const int* in_sizes, int n_in,
                              void* d_out, int out_size, void* d_ws, size_t ws_size,
                              hipStream_t stream) {
    const float* coords = (const float*)d_in[0];
    const float* fields = (const float*)d_in[1];
    const int*   ip0    = (const int*)d_in[2];
    const int*   ix0    = (const int*)d_in[3];
    const int*   ip1    = (const int*)d_in[4];
    const int*   ix1    = (const int*)d_in[5];
    const float* W_in   = (const float*)d_in[6];
    const float* b_in   = (const float*)d_in[7];
    const float* Wq     = (const float*)d_in[8];
    const float* Wk     = (const float*)d_in[9];
    const float* Wv     = (const float*)d_in[10];
    const float* Wo     = (const float*)d_in[11];
    const float* bo     = (const float*)d_in[12];

    int n = in_sizes[0] / 2;          // coords is [N,2]
    float* x = (float*)d_out;         // x lives in d_out throughout

    char* ws = (char*)d_ws;
    size_t off = 0;
    auto carve = [&](size_t bytes) {
        void* p = ws + off;
        off = (off + bytes + 255) & ~(size_t)255;
        return p;
    };
    float*  geom = (float*)carve((size_t)n * 6 * 4);
    __half* qh   = (__half*)carve((size_t)n * 64 * 2);
    __half* kh   = (__half*)carve((size_t)n * 64 * 2);
    __half* vh   = (__half*)carve((size_t)n * 128 * 2);
    float*  agg  = (float*)carve((size_t)n * 256 * 4);

    geom_kernel<<<(n + 255) / 256, 256, 0, stream>>>(coords, ip0, ix0, ip1, ix1, geom, n);
    prologue_kernel<<<(n + 1) / 2, 256, 0, stream>>>(fields, geom, W_in, b_in, x, n);

    int deg0 = in_sizes[3] / n;
    int deg1 = in_sizes[5] / n;

    auto launch_attn = [&](int deg, const int* ip, const int* ix, int scale) {
        int ab = (n + 3) / 4;
        bool uniform = (deg * n == (scale ? in_sizes[5] : in_sizes[3]));
        if (uniform) {
            switch (deg) {
                case 4:  attn_kernel_t<4><<<ab, 256, 0, stream>>>(qh, kh, vh, ip, ix, agg, scale, n); return;
                case 6:  attn_kernel_t<6><<<ab, 256, 0, stream>>>(qh, kh, vh, ip, ix, agg, scale, n); return;
                case 8:  attn_kernel_t<8><<<ab, 256, 0, stream>>>(qh, kh, vh, ip, ix, agg, scale, n); return;
                case 12: attn_kernel_t<12><<<ab, 256, 0, stream>>>(qh, kh, vh, ip, ix, agg, scale, n); return;
                case 16: attn_kernel_t<16><<<ab, 256, 0, stream>>>(qh, kh, vh, ip, ix, agg, scale, n); return;
            }
        }
        attn_generic<<<ab, 256, 0, stream>>>(qh, kh, vh, ip, ix, agg, scale, n);
    };

    int gblocks = (n + 63) / 64;
    for (int l = 0; l < 3; ++l) {
        for (int s = 0; s < 2; ++s) {
            const float* wq = Wq + (size_t)(l * 2 + s) * 128 * 64;
            const float* wk = Wk + (size_t)(l * 2 + s) * 128 * 64;
            const float* wv = Wv + (size_t)(l * 2 + s) * 128 * 128;
            qkv_gemm_kernel<<<gblocks, 256, 0, stream>>>(x, wq, wk, wv, qh, kh, vh, n);
            launch_attn(s ? deg1 : deg0, s ? ip1 : ip0, s ? ix1 : ix0, s);
        }
        wo_gemm_kernel<<<gblocks, 256, 0, stream>>>(agg, Wo + (size_t)l * 256 * 128,
                                                    bo + l * 128, x, n);
    }
}

// Round 5
// 593.682 us; speedup vs baseline: 2.0019x; 1.6894x over previous
//
#include <hip/hip_runtime.h>
#include <hip/hip_fp16.h>
#include <math.h>

#define HD 128

typedef _Float16 f16x8 __attribute__((ext_vector_type(8)));
typedef float f32x4 __attribute__((ext_vector_type(4)));

__device__ __forceinline__ f16x8 f16x8_zero() {
    f16x8 v = {(_Float16)0, (_Float16)0, (_Float16)0, (_Float16)0,
               (_Float16)0, (_Float16)0, (_Float16)0, (_Float16)0};
    return v;
}

__device__ __forceinline__ float gelu_tanh(float v) {
    float v3 = v * v * v;
    float t = tanhf(0.7978845608028654f * (v + 0.044715f * v3));
    return 0.5f * v * (1.0f + t);
}

__device__ __forceinline__ void store_h4(__half* p, float4 a) {
    __half2 lo = __float22half2_rn(make_float2(a.x, a.y));
    __half2 hi = __float22half2_rn(make_float2(a.z, a.w));
    uint2 u;
    u.x = *(unsigned*)&lo;
    u.y = *(unsigned*)&hi;
    *(uint2*)p = u;
}

__device__ __forceinline__ float4 load_h4(const __half* p) {
    uint2 raw = *(const uint2*)p;
    float2 lo = __half22float2(*(__half2*)&raw.x);
    float2 hi = __half22float2(*(__half2*)&raw.y);
    return make_float4(lo.x, lo.y, hi.x, hi.y);
}

// ---------------- weight conversion: W^T fp16 buffers (once per launch) -------
// Wt[ls][oc][k], oc in [0,256): 0-63 Wq, 64-127 Wk, 128-255 Wv; k in [0,128)
__global__ void convert_wqkv_kernel(const float* __restrict__ Wq,
                                    const float* __restrict__ Wk,
                                    const float* __restrict__ Wv,
                                    __half* __restrict__ Wt) {
    int idx = blockIdx.x * 256 + threadIdx.x;
    if (idx >= 6 * 256 * 32) return;
    int ls = idx / (256 * 32);
    int rem = idx - ls * (256 * 32);
    int oc = rem >> 5;
    int k4 = rem & 31;
    const float* src;
    int stride, col;
    if (oc < 64)       { src = Wq + (size_t)ls * 128 * 64;  stride = 64;  col = oc; }
    else if (oc < 128) { src = Wk + (size_t)ls * 128 * 64;  stride = 64;  col = oc - 64; }
    else               { src = Wv + (size_t)ls * 128 * 128; stride = 128; col = oc - 128; }
    float4 v;
    v.x = src[(k4 * 4 + 0) * stride + col];
    v.y = src[(k4 * 4 + 1) * stride + col];
    v.z = src[(k4 * 4 + 2) * stride + col];
    v.w = src[(k4 * 4 + 3) * stride + col];
    store_h4(&Wt[(size_t)ls * 256 * 128 + (size_t)oc * 128 + k4 * 4], v);
}

// Wot[l][oc][k], oc in [0,128), k in [0,256)
__global__ void convert_wo_kernel(const float* __restrict__ Wo,
                                  __half* __restrict__ Wot) {
    int idx = blockIdx.x * 256 + threadIdx.x;
    if (idx >= 3 * 128 * 64) return;
    int l = idx / (128 * 64);
    int rem = idx - l * (128 * 64);
    int oc = rem >> 6;
    int k4 = rem & 63;
    const float* src = Wo + (size_t)l * 256 * 128;
    float4 v;
    v.x = src[(k4 * 4 + 0) * 128 + oc];
    v.y = src[(k4 * 4 + 1) * 128 + oc];
    v.z = src[(k4 * 4 + 2) * 128 + oc];
    v.w = src[(k4 * 4 + 3) * 128 + oc];
    store_h4(&Wot[(size_t)l * 128 * 256 + (size_t)oc * 256 + k4 * 4], v);
}

// ---------------- geometry: per-node mean rel offset + mean dist per scale ----
__global__ void geom_kernel(const float* __restrict__ coords,
                            const int* __restrict__ ip0, const int* __restrict__ ix0,
                            const int* __restrict__ ip1, const int* __restrict__ ix1,
                            float* __restrict__ geom, int n) {
    int i = blockIdx.x * blockDim.x + threadIdx.x;
    if (i >= n) return;
    float cx = coords[2 * i], cy = coords[2 * i + 1];
    #pragma unroll
    for (int s = 0; s < 2; ++s) {
        const int* ip = s ? ip1 : ip0;
        const int* ix = s ? ix1 : ix0;
        int st = ip[i], en = ip[i + 1];
        float sx = 0.f, sy = 0.f, sd = 0.f;
        for (int e = st; e < en; ++e) {
            int c = ix[e];
            float dx = coords[2 * c] - cx;
            float dy = coords[2 * c + 1] - cy;
            sx += dx; sy += dy;
            sd += sqrtf(dx * dx + dy * dy);
        }
        float inv = 1.0f / fmaxf((float)(en - st), 1.0f);
        geom[6 * i + 3 * s + 0] = sx * inv;
        geom[6 * i + 3 * s + 1] = sy * inv;
        geom[6 * i + 3 * s + 2] = sd * inv;
    }
}

// ---------------- prologue: x = gelu([fields|geom] @ W_in + b_in), + fp16 copy
__global__ void prologue_kernel(const float* __restrict__ fields,
                                const float* __restrict__ geom,
                                const float* __restrict__ W_in,
                                const float* __restrict__ b_in,
                                float* __restrict__ x,
                                __half* __restrict__ xh, int n) {
    int node = blockIdx.x * 2 + (threadIdx.x >> 7);
    int col = threadIdx.x & 127;
    if (node >= n) return;
    float acc = b_in[col];
    const float* f = fields + (size_t)node * 16;
    const float* g = geom + (size_t)node * 6;
    #pragma unroll
    for (int k = 0; k < 16; ++k) acc += f[k] * W_in[k * HD + col];
    #pragma unroll
    for (int k = 0; k < 6; ++k) acc += g[k] * W_in[(16 + k) * HD + col];
    float r = gelu_tanh(acc);
    x[(size_t)node * HD + col] = r;
    xh[(size_t)node * HD + col] = __float2half(r);
}

// ---------------- QKV MFMA: D^T = W^T (A) x X^T (B), fused q/k norm ----------
// block = 64 nodes, 4 waves; wave w owns outcols [w*64, w*64+64)
// w=0 -> q (normed), w=1 -> k (normed), w=2/3 -> v halves
__global__ __launch_bounds__(256)
void qkv_mfma_kernel(const __half* __restrict__ xh,    // [N,128]
                     const __half* __restrict__ Wt,    // [256,128] = W^T
                     __half* __restrict__ qh,          // [N,64]
                     __half* __restrict__ kh,          // [N,64]
                     __half* __restrict__ vh,          // [N,128]
                     int n) {
    __shared__ __half Xs[64 * 128];                    // 16 KB, XOR-swizzled
    int t = threadIdx.x;
    int lane = t & 63, w = t >> 6;
    int m0 = blockIdx.x * 64;

    #pragma unroll
    for (int it = 0; it < 4; ++it) {
        int idx = t + it * 256;                        // 0..1023
        int row = idx >> 4, slot = idx & 15;
        int sw = slot ^ (row & 7);
        f16x8 v = f16x8_zero();
        if (m0 + row < n)
            v = *(const f16x8*)&xh[(size_t)(m0 + row) * 128 + slot * 8];
        *(f16x8*)&Xs[row * 128 + sw * 8] = v;
    }
    __syncthreads();

    int lr = lane & 15, lq = lane >> 4;
    f32x4 acc[4][4];
    #pragma unroll
    for (int nf = 0; nf < 4; ++nf)
        #pragma unroll
        for (int of = 0; of < 4; ++of) {
            f32x4 z = {0.f, 0.f, 0.f, 0.f};
            acc[nf][of] = z;
        }

    const __half* Wbase = Wt + (size_t)(w * 64) * 128;
    #pragma unroll
    for (int ts = 0; ts < 4; ++ts) {
        int koct = ts * 4 + lq;
        f16x8 wf[4], xf[4];
        #pragma unroll
        for (int of = 0; of < 4; ++of)
            wf[of] = *(const f16x8*)&Wbase[(size_t)(of * 16 + lr) * 128 + koct * 8];
        #pragma unroll
        for (int nf = 0; nf < 4; ++nf) {
            int row = nf * 16 + lr;
            int sw = koct ^ (row & 7);
            xf[nf] = *(const f16x8*)&Xs[row * 128 + sw * 8];
        }
        #pragma unroll
        for (int nf = 0; nf < 4; ++nf)
            #pragma unroll
            for (int of = 0; of < 4; ++of)
                acc[nf][of] = __builtin_amdgcn_mfma_f32_16x16x32_f16(
                    wf[of], xf[nf], acc[nf][of], 0, 0, 0);
    }

    // cosine-normalize: q (w==0) and k (w==1); lanes {l, l^16, l^32, l^48} share a node
    if (w < 2) {
        #pragma unroll
        for (int nf = 0; nf < 4; ++nf) {
            float s = 0.f;
            #pragma unroll
            for (int of = 0; of < 4; ++of) {
                f32x4 a = acc[nf][of];
                s += a[0] * a[0] + a[1] * a[1] + a[2] * a[2] + a[3] * a[3];
            }
            s += __shfl_xor(s, 16, 64);
            s += __shfl_xor(s, 32, 64);
            float f = 1.0f / (sqrtf(s) + 1e-6f);
            #pragma unroll
            for (int of = 0; of < 4; ++of) {
                acc[nf][of][0] *= f; acc[nf][of][1] *= f;
                acc[nf][of][2] *= f; acc[nf][of][3] *= f;
            }
        }
    }

    #pragma unroll
    for (int nf = 0; nf < 4; ++nf) {
        int node = m0 + nf * 16 + lr;
        if (node >= n) continue;
        #pragma unroll
        for (int of = 0; of < 4; ++of) {
            int oc = of * 16 + lq * 4;                 // within wave's 64-col slice
            float4 v = make_float4(acc[nf][of][0], acc[nf][of][1],
                                   acc[nf][of][2], acc[nf][of][3]);
            if (w == 0)      store_h4(&qh[(size_t)node * 64 + oc], v);
            else if (w == 1) store_h4(&kh[(size_t)node * 64 + oc], v);
            else if (w == 2) store_h4(&vh[(size_t)node * 128 + oc], v);
            else             store_h4(&vh[(size_t)node * 128 + 64 + oc], v);
        }
    }
}

// ---------------- attention: one wave per node, degree templated --------------
template<int DEG>
__global__ void attn_kernel_t(const __half* __restrict__ qh,
                              const __half* __restrict__ kh,
                              const __half* __restrict__ vh,
                              const int* __restrict__ indptr,
                              const int* __restrict__ indices,
                              __half* __restrict__ aggh,   // [N,256]
                              int scale, int n) {
    int wid = threadIdx.x >> 6;
    int lane = threadIdx.x & 63;
    int i = blockIdx.x * (blockDim.x >> 6) + wid;
    if (i >= n) return;
    int g = lane >> 4, sl = lane & 15;
    int st = indptr[i];

    float4 q = load_h4(&qh[(size_t)i * 64 + sl * 4]);

    float sc[DEG];
    constexpr int NIT = (DEG + 3) / 4;
    #pragma unroll
    for (int it = 0; it < NIT; ++it) {
        int e = it * 4 + g;
        int ee = (e < DEG) ? e : (DEG - 1);
        int c = indices[st + ee];
        float4 k = load_h4(&kh[(size_t)c * 64 + sl * 4]);
        float p = q.x * k.x + q.y * k.y + q.z * k.z + q.w * k.w;
        p += __shfl_xor(p, 1, 64);
        p += __shfl_xor(p, 2, 64);
        p += __shfl_xor(p, 4, 64);
        p += __shfl_xor(p, 8, 64);
        #pragma unroll
        for (int j = 0; j < 4; ++j) {
            int e2 = it * 4 + j;
            if (e2 < DEG) sc[e2] = __shfl(p, j * 16, 64);
        }
    }

    float mx = sc[0];
    #pragma unroll
    for (int e = 1; e < DEG; ++e) mx = fmaxf(mx, sc[e]);
    float den = 0.f;
    #pragma unroll
    for (int e = 0; e < DEG; ++e) { sc[e] = __expf(sc[e] - mx); den += sc[e]; }
    float inv = 1.0f / den;

    int half = lane >> 5, hl = lane & 31;
    float4 a = make_float4(0.f, 0.f, 0.f, 0.f);
    #pragma unroll
    for (int it = 0; it < DEG / 2; ++it) {
        int c = indices[st + 2 * it + half];
        float al = (half ? sc[2 * it + 1] : sc[2 * it]) * inv;
        float4 v = load_h4(&vh[(size_t)c * 128 + hl * 4]);
        a.x += al * v.x; a.y += al * v.y; a.z += al * v.z; a.w += al * v.w;
    }
    a.x += __shfl_xor(a.x, 32, 64);
    a.y += __shfl_xor(a.y, 32, 64);
    a.z += __shfl_xor(a.z, 32, 64);
    a.w += __shfl_xor(a.w, 32, 64);
    if (half == 0)
        store_h4(&aggh[(size_t)i * 256 + scale * 128 + hl * 4], a);
}

// generic fallback (any degree up to 32)
__global__ void attn_generic(const __half* __restrict__ qh,
                             const __half* __restrict__ kh,
                             const __half* __restrict__ vh,
                             const int* __restrict__ indptr,
                             const int* __restrict__ indices,
                             __half* __restrict__ aggh, int scale, int n) {
    int wid = threadIdx.x >> 6;
    int lane = threadIdx.x & 63;
    int i = blockIdx.x * (blockDim.x >> 6) + wid;
    if (i >= n) return;
    int g = lane >> 4, sl = lane & 15;
    int st = indptr[i];
    int deg = indptr[i + 1] - st;
    if (deg > 32) deg = 32;
    if (deg <= 0) {
        if (lane < 32)
            store_h4(&aggh[(size_t)i * 256 + scale * 128 + (lane & 31) * 4],
                     make_float4(0.f, 0.f, 0.f, 0.f));
        return;
    }
    float4 q = load_h4(&qh[(size_t)i * 64 + sl * 4]);
    float sc[32];
    for (int e0 = 0; e0 < deg; e0 += 4) {
        int e = e0 + g;
        int ee = (e < deg) ? e : (deg - 1);
        int c = indices[st + ee];
        float4 k = load_h4(&kh[(size_t)c * 64 + sl * 4]);
        float p = q.x * k.x + q.y * k.y + q.z * k.z + q.w * k.w;
        p += __shfl_xor(p, 1, 64);
        p += __shfl_xor(p, 2, 64);
        p += __shfl_xor(p, 4, 64);
        p += __shfl_xor(p, 8, 64);
        for (int j = 0; j < 4; ++j)
            if (e0 + j < deg) sc[e0 + j] = __shfl(p, j * 16, 64);
    }
    float mx = -INFINITY;
    for (int e = 0; e < deg; ++e) mx = fmaxf(mx, sc[e]);
    float den = 0.f;
    for (int e = 0; e < deg; ++e) { sc[e] = __expf(sc[e] - mx); den += sc[e]; }
    float inv = 1.0f / den;
    int half = lane >> 5, hl = lane & 31;
    float4 a = make_float4(0.f, 0.f, 0.f, 0.f);
    for (int e0 = 0; e0 < deg; e0 += 2) {
        int e = e0 + half;
        if (e < deg) {
            int c = indices[st + e];
            float al = sc[e] * inv;
            float4 v = load_h4(&vh[(size_t)c * 128 + hl * 4]);
            a.x += al * v.x; a.y += al * v.y; a.z += al * v.z; a.w += al * v.w;
        }
    }
    a.x += __shfl_xor(a.x, 32, 64);
    a.y += __shfl_xor(a.y, 32, 64);
    a.z += __shfl_xor(a.z, 32, 64);
    a.w += __shfl_xor(a.w, 32, 64);
    if (half == 0)
        store_h4(&aggh[(size_t)i * 256 + scale * 128 + hl * 4], a);
}

// ---------------- Wo MFMA: x += gelu(agg @ Wo + bo), D^T layout ---------------
// block = 64 nodes x 128 outcols, 4 waves; wave w owns outcols [w*32, w*32+32)
__global__ __launch_bounds__(256)
void wo_mfma_kernel(const __half* __restrict__ aggh,   // [N,256]
                    const __half* __restrict__ Wot,    // [128,256] = Wo^T
                    const float* __restrict__ bo,      // [128]
                    float* __restrict__ x,             // [N,128] residual io
                    __half* __restrict__ xh,           // [N,128] fp16 copy
                    int n) {
    __shared__ __half As[64 * 256];                    // 32 KB, XOR-swizzled
    int t = threadIdx.x;
    int lane = t & 63, w = t >> 6;
    int m0 = blockIdx.x * 64;

    #pragma unroll
    for (int it = 0; it < 8; ++it) {
        int idx = t + it * 256;                        // 0..2047
        int row = idx >> 5, slot = idx & 31;
        int sw = slot ^ (row & 7);
        f16x8 v = f16x8_zero();
        if (m0 + row < n)
            v = *(const f16x8*)&aggh[(size_t)(m0 + row) * 256 + slot * 8];
        *(f16x8*)&As[row * 256 + sw * 8] = v;
    }
    __syncthreads();

    int lr = lane & 15, lq = lane >> 4;
    f32x4 acc[4][2];
    #pragma unroll
    for (int nf = 0; nf < 4; ++nf)
        #pragma unroll
        for (int of = 0; of < 2; ++of) {
            f32x4 z = {0.f, 0.f, 0.f, 0.f};
            acc[nf][of] = z;
        }

    const __half* Wbase = Wot + (size_t)(w * 32) * 256;
    #pragma unroll
    for (int ts = 0; ts < 8; ++ts) {
        int koct = ts * 4 + lq;
        f16x8 wf[2], af[4];
        #pragma unroll
        for (int of = 0; of < 2; ++of)
            wf[of] = *(const f16x8*)&Wbase[(size_t)(of * 16 + lr) * 256 + koct * 8];
        #pragma unroll
        for (int nf = 0; nf < 4; ++nf) {
            int row = nf * 16 + lr;
            int sw = koct ^ (row & 7);
            af[nf] = *(const f16x8*)&As[row * 256 + sw * 8];
        }
        #pragma unroll
        for (int nf = 0; nf < 4; ++nf)
            #pragma unroll
            for (int of = 0; of < 2; ++of)
                acc[nf][of] = __builtin_amdgcn_mfma_f32_16x16x32_f16(
                    wf[of], af[nf], acc[nf][of], 0, 0, 0);
    }

    #pragma unroll
    for (int nf = 0; nf < 4; ++nf) {
        int node = m0 + nf * 16 + lr;
        if (node >= n) continue;
        #pragma unroll
        for (int of = 0; of < 2; ++of) {
            int oc = w * 32 + of * 16 + lq * 4;
            float4 b = *(const float4*)&bo[oc];
            float4 xv = *(const float4*)&x[(size_t)node * 128 + oc];
            float4 r;
            r.x = xv.x + gelu_tanh(acc[nf][of][0] + b.x);
            r.y = xv.y + gelu_tanh(acc[nf][of][1] + b.y);
            r.z = xv.z + gelu_tanh(acc[nf][of][2] + b.z);
            r.w = xv.w + gelu_tanh(acc[nf][of][3] + b.w);
            *(float4*)&x[(size_t)node * 128 + oc] = r;
            store_h4(&xh[(size_t)node * 128 + oc], r);
        }
    }
}

extern "C" void kernel_launch(void* const* d_in, const int* in_sizes, int n_in,
                              void* d_out, int out_size, void* d_ws, size_t ws_size,
                              hipStream_t stream) {
    const float* coords = (const float*)d_in[0];
    const float* fields = (const float*)d_in[1];
    const int*   ip0    = (const int*)d_in[2];
    const int*   ix0    = (const int*)d_in[3];
    const int*   ip1    = (const int*)d_in[4];
    const int*   ix1    = (const int*)d_in[5];
    const float* W_in   = (const float*)d_in[6];
    const float* b_in   = (const float*)d_in[7];
    const float* Wq     = (const float*)d_in[8];
    const float* Wk     = (const float*)d_in[9];
    const float* Wv     = (const float*)d_in[10];
    const float* Wo     = (const float*)d_in[11];
    const float* bo     = (const float*)d_in[12];

    int n = in_sizes[0] / 2;          // coords is [N,2]
    float* x = (float*)d_out;         // x lives in d_out throughout

    char* ws = (char*)d_ws;
    size_t off = 0;
    auto carve = [&](size_t bytes) {
        void* p = ws + off;
        off = (off + bytes + 255) & ~(size_t)255;
        return p;
    };
    float*  geom = (float*)carve((size_t)n * 6 * 4);
    __half* xh   = (__half*)carve((size_t)n * 128 * 2);
    __half* qh   = (__half*)carve((size_t)n * 64 * 2);
    __half* kh   = (__half*)carve((size_t)n * 64 * 2);
    __half* vh   = (__half*)carve((size_t)n * 128 * 2);
    __half* aggh = (__half*)carve((size_t)n * 256 * 2);
    __half* Wt   = (__half*)carve((size_t)6 * 256 * 128 * 2);
    __half* Wot  = (__half*)carve((size_t)3 * 128 * 256 * 2);

    convert_wqkv_kernel<<<(6 * 256 * 32 + 255) / 256, 256, 0, stream>>>(Wq, Wk, Wv, Wt);
    convert_wo_kernel<<<(3 * 128 * 64 + 255) / 256, 256, 0, stream>>>(Wo, Wot);

    geom_kernel<<<(n + 255) / 256, 256, 0, stream>>>(coords, ip0, ix0, ip1, ix1, geom, n);
    prologue_kernel<<<(n + 1) / 2, 256, 0, stream>>>(fields, geom, W_in, b_in, x, xh, n);

    int deg0 = in_sizes[3] / n;
    int deg1 = in_sizes[5] / n;

    auto launch_attn = [&](int deg, const int* ip, const int* ix, int scale) {
        int ab = (n + 3) / 4;
        bool uniform = (deg * n == (scale ? in_sizes[5] : in_sizes[3]));
        if (uniform) {
            switch (deg) {
                case 4:  attn_kernel_t<4><<<ab, 256, 0, stream>>>(qh, kh, vh, ip, ix, aggh, scale, n); return;
                case 6:  attn_kernel_t<6><<<ab, 256, 0, stream>>>(qh, kh, vh, ip, ix, aggh, scale, n); return;
                case 8:  attn_kernel_t<8><<<ab, 256, 0, stream>>>(qh, kh, vh, ip, ix, aggh, scale, n); return;
                case 12: attn_kernel_t<12><<<ab, 256, 0, stream>>>(qh, kh, vh, ip, ix, aggh, scale, n); return;
                case 16: attn_kernel_t<16><<<ab, 256, 0, stream>>>(qh, kh, vh, ip, ix, aggh, scale, n); return;
            }
        }
        attn_generic<<<ab, 256, 0, stream>>>(qh, kh, vh, ip, ix, aggh, scale, n);
    };

    int gblocks = (n + 63) / 64;
    for (int l = 0; l < 3; ++l) {
        for (int s = 0; s < 2; ++s) {
            const __half* wt = Wt + (size_t)(l * 2 + s) * 256 * 128;
            qkv_mfma_kernel<<<gblocks, 256, 0, stream>>>(xh, wt, qh, kh, vh, n);
            launch_attn(s ? deg1 : deg0, s ? ip1 : ip0, s ? ix1 : ix0, s);
        }
        wo_mfma_kernel<<<gblocks, 256, 0, stream>>>(aggh, Wot + (size_t)l * 128 * 256,
                                                    bo + l * 128, x, xh, n);
    }
}

// Round 12
// 570.516 us; speedup vs baseline: 2.0832x; 1.0406x over previous
//
#include <hip/hip_runtime.h>
#include <hip/hip_fp16.h>
#include <math.h>

#define HD 128

typedef _Float16 f16x8 __attribute__((ext_vector_type(8)));
typedef float f32x4 __attribute__((ext_vector_type(4)));

__device__ __forceinline__ f16x8 f16x8_zero() {
    f16x8 v = {(_Float16)0, (_Float16)0, (_Float16)0, (_Float16)0,
               (_Float16)0, (_Float16)0, (_Float16)0, (_Float16)0};
    return v;
}

__device__ __forceinline__ float gelu_tanh(float v) {
    float v3 = v * v * v;
    float t = tanhf(0.7978845608028654f * (v + 0.044715f * v3));
    return 0.5f * v * (1.0f + t);
}

__device__ __forceinline__ void store_h4(__half* p, float4 a) {
    __half2 lo = __float22half2_rn(make_float2(a.x, a.y));
    __half2 hi = __float22half2_rn(make_float2(a.z, a.w));
    uint2 u;
    u.x = *(unsigned*)&lo;
    u.y = *(unsigned*)&hi;
    *(uint2*)p = u;
}

__device__ __forceinline__ float4 load_h4(const __half* p) {
    uint2 raw = *(const uint2*)p;
    float2 lo = __half22float2(*(__half2*)&raw.x);
    float2 hi = __half22float2(*(__half2*)&raw.y);
    return make_float4(lo.x, lo.y, hi.x, hi.y);
}

// ---------------- weight conversion: W^T fp16 buffers (once per launch) -------
__global__ void convert_wqkv_kernel(const float* __restrict__ Wq,
                                    const float* __restrict__ Wk,
                                    const float* __restrict__ Wv,
                                    __half* __restrict__ Wt) {
    int idx = blockIdx.x * 256 + threadIdx.x;
    if (idx >= 6 * 256 * 32) return;
    int ls = idx / (256 * 32);
    int rem = idx - ls * (256 * 32);
    int oc = rem >> 5;
    int k4 = rem & 31;
    const float* src;
    int stride, col;
    if (oc < 64)       { src = Wq + (size_t)ls * 128 * 64;  stride = 64;  col = oc; }
    else if (oc < 128) { src = Wk + (size_t)ls * 128 * 64;  stride = 64;  col = oc - 64; }
    else               { src = Wv + (size_t)ls * 128 * 128; stride = 128; col = oc - 128; }
    float4 v;
    v.x = src[(k4 * 4 + 0) * stride + col];
    v.y = src[(k4 * 4 + 1) * stride + col];
    v.z = src[(k4 * 4 + 2) * stride + col];
    v.w = src[(k4 * 4 + 3) * stride + col];
    store_h4(&Wt[(size_t)ls * 256 * 128 + (size_t)oc * 128 + k4 * 4], v);
}

__global__ void convert_wo_kernel(const float* __restrict__ Wo,
                                  __half* __restrict__ Wot) {
    int idx = blockIdx.x * 256 + threadIdx.x;
    if (idx >= 3 * 128 * 64) return;
    int l = idx / (128 * 64);
    int rem = idx - l * (128 * 64);
    int oc = rem >> 6;
    int k4 = rem & 63;
    const float* src = Wo + (size_t)l * 256 * 128;
    float4 v;
    v.x = src[(k4 * 4 + 0) * 128 + oc];
    v.y = src[(k4 * 4 + 1) * 128 + oc];
    v.z = src[(k4 * 4 + 2) * 128 + oc];
    v.w = src[(k4 * 4 + 3) * 128 + oc];
    store_h4(&Wot[(size_t)l * 128 * 256 + (size_t)oc * 256 + k4 * 4], v);
}

// ---------------- fused geometry + prologue -----------------------------------
// block = 2 nodes x 128 cols. Phase 1: col==0 thread of each node computes the
// 6 geom values (byte-identical code to the old geom_kernel) into LDS.
// Phase 2: x = gelu([fields|geom] @ W_in + b_in), + fp16 copy.
__global__ void geom_prologue_kernel(const float* __restrict__ coords,
                                     const float* __restrict__ fields,
                                     const int* __restrict__ ip0, const int* __restrict__ ix0,
                                     const int* __restrict__ ip1, const int* __restrict__ ix1,
                                     const float* __restrict__ W_in,
                                     const float* __restrict__ b_in,
                                     float* __restrict__ x,
                                     __half* __restrict__ xh, int n) {
    __shared__ float gsh[2][6];
    int slot = threadIdx.x >> 7;              // 0 or 1: node within block
    int node = blockIdx.x * 2 + slot;
    int col = threadIdx.x & 127;
    bool valid = node < n;

    if (valid && col == 0) {
        float cx = coords[2 * node], cy = coords[2 * node + 1];
        #pragma unroll
        for (int s = 0; s < 2; ++s) {
            const int* ip = s ? ip1 : ip0;
            const int* ix = s ? ix1 : ix0;
            int st = ip[node], en = ip[node + 1];
            float sx = 0.f, sy = 0.f, sd = 0.f;
            for (int e = st; e < en; ++e) {
                int c = ix[e];
                float dx = coords[2 * c] - cx;
                float dy = coords[2 * c + 1] - cy;
                sx += dx; sy += dy;
                sd += sqrtf(dx * dx + dy * dy);
            }
            float inv = 1.0f / fmaxf((float)(en - st), 1.0f);
            gsh[slot][3 * s + 0] = sx * inv;
            gsh[slot][3 * s + 1] = sy * inv;
            gsh[slot][3 * s + 2] = sd * inv;
        }
    }
    __syncthreads();                          // all threads reach this
    if (!valid) return;

    float acc = b_in[col];
    const float* f = fields + (size_t)node * 16;
    #pragma unroll
    for (int k = 0; k < 16; ++k) acc += f[k] * W_in[k * HD + col];
    #pragma unroll
    for (int k = 0; k < 6; ++k) acc += gsh[slot][k] * W_in[(16 + k) * HD + col];
    float r = gelu_tanh(acc);
    x[(size_t)node * HD + col] = r;
    xh[(size_t)node * HD + col] = __float2half(r);
}

// ---------------- dual-scale QKV MFMA: D^T = W^T x X^T, fused q/k norm --------
// block = 64 nodes, 8 waves (512 thr); wave w: scale=w>>2, sub=w&3
// sub 0 -> q (normed), 1 -> k (normed), 2/3 -> v halves
__global__ __launch_bounds__(512)
void qkv_dual_mfma_kernel(const __half* __restrict__ xh,    // [N,128]
                          const __half* __restrict__ WtL,   // [2][256][128]
                          __half* __restrict__ qh0, __half* __restrict__ kh0,
                          __half* __restrict__ vh0,
                          __half* __restrict__ qh1, __half* __restrict__ kh1,
                          __half* __restrict__ vh1,
                          int n) {
    __shared__ __half Xs[64 * 128];                    // 16 KB, XOR-swizzled
    int t = threadIdx.x;
    int lane = t & 63, w = t >> 6;
    int m0 = blockIdx.x * 64;

    #pragma unroll
    for (int it = 0; it < 2; ++it) {
        int idx = t + it * 512;                        // 0..1023
        int row = idx >> 4, slot = idx & 15;
        int sw = slot ^ (row & 7);
        f16x8 v = f16x8_zero();
        if (m0 + row < n)
            v = *(const f16x8*)&xh[(size_t)(m0 + row) * 128 + slot * 8];
        *(f16x8*)&Xs[row * 128 + sw * 8] = v;
    }
    __syncthreads();

    int scale = w >> 2, sub = w & 3;
    int lr = lane & 15, lq = lane >> 4;
    f32x4 acc[4][4];
    #pragma unroll
    for (int nf = 0; nf < 4; ++nf)
        #pragma unroll
        for (int of = 0; of < 4; ++of) {
            f32x4 z = {0.f, 0.f, 0.f, 0.f};
            acc[nf][of] = z;
        }

    const __half* Wbase = WtL + ((size_t)scale * 256 + sub * 64) * 128;
    #pragma unroll
    for (int ts = 0; ts < 4; ++ts) {
        int koct = ts * 4 + lq;
        f16x8 wf[4], xf[4];
        #pragma unroll
        for (int of = 0; of < 4; ++of)
            wf[of] = *(const f16x8*)&Wbase[(size_t)(of * 16 + lr) * 128 + koct * 8];
        #pragma unroll
        for (int nf = 0; nf < 4; ++nf) {
            int row = nf * 16 + lr;
            int sw = koct ^ (row & 7);
            xf[nf] = *(const f16x8*)&Xs[row * 128 + sw * 8];
        }
        #pragma unroll
        for (int nf = 0; nf < 4; ++nf)
            #pragma unroll
            for (int of = 0; of < 4; ++of)
                acc[nf][of] = __builtin_amdgcn_mfma_f32_16x16x32_f16(
                    wf[of], xf[nf], acc[nf][of], 0, 0, 0);
    }

    if (sub < 2) {   // cosine-normalize q/k; lanes {l, l^16, l^32, l^48} share a node
        #pragma unroll
        for (int nf = 0; nf < 4; ++nf) {
            float s = 0.f;
            #pragma unroll
            for (int of = 0; of < 4; ++of) {
                f32x4 a = acc[nf][of];
                s += a[0] * a[0] + a[1] * a[1] + a[2] * a[2] + a[3] * a[3];
            }
            s += __shfl_xor(s, 16, 64);
            s += __shfl_xor(s, 32, 64);
            float f = 1.0f / (sqrtf(s) + 1e-6f);
            #pragma unroll
            for (int of = 0; of < 4; ++of) {
                acc[nf][of][0] *= f; acc[nf][of][1] *= f;
                acc[nf][of][2] *= f; acc[nf][of][3] *= f;
            }
        }
    }

    __half* qh = scale ? qh1 : qh0;
    __half* kh = scale ? kh1 : kh0;
    __half* vh = scale ? vh1 : vh0;
    #pragma unroll
    for (int nf = 0; nf < 4; ++nf) {
        int node = m0 + nf * 16 + lr;
        if (node >= n) continue;
        #pragma unroll
        for (int of = 0; of < 4; ++of) {
            int oc = of * 16 + lq * 4;
            float4 v = make_float4(acc[nf][of][0], acc[nf][of][1],
                                   acc[nf][of][2], acc[nf][of][3]);
            if (sub == 0)      store_h4(&qh[(size_t)node * 64 + oc], v);
            else if (sub == 1) store_h4(&kh[(size_t)node * 64 + oc], v);
            else if (sub == 2) store_h4(&vh[(size_t)node * 128 + oc], v);
            else               store_h4(&vh[(size_t)node * 128 + 64 + oc], v);
        }
    }
}

// ---------------- attention core: one wave per (node,scale), MLP-batched ------
template<int DEG>
__device__ __forceinline__ void attn_one(const __half* __restrict__ qh,
                                         const __half* __restrict__ kh,
                                         const __half* __restrict__ vh,
                                         const int* __restrict__ ixs,   // indices+st
                                         __half* __restrict__ out,      // agg slice
                                         int node, int lane) {
    int g = lane >> 4, sl = lane & 15;
    constexpr int NIT = (DEG + 3) / 4;

    // batch index loads, then batch k gathers (MLP), then dots+reduce
    int cidx[NIT];
    #pragma unroll
    for (int it = 0; it < NIT; ++it) {
        int e = it * 4 + g;
        cidx[it] = ixs[(e < DEG) ? e : (DEG - 1)];
    }
    float4 q = load_h4(&qh[(size_t)node * 64 + sl * 4]);
    uint2 kraw[NIT];
    #pragma unroll
    for (int it = 0; it < NIT; ++it)
        kraw[it] = *(const uint2*)&kh[(size_t)cidx[it] * 64 + sl * 4];

    float sc[DEG];
    #pragma unroll
    for (int it = 0; it < NIT; ++it) {
        float2 lo = __half22float2(*(__half2*)&kraw[it].x);
        float2 hi = __half22float2(*(__half2*)&kraw[it].y);
        float p = q.x * lo.x + q.y * lo.y + q.z * hi.x + q.w * hi.y;
        p += __shfl_xor(p, 1, 64);
        p += __shfl_xor(p, 2, 64);
        p += __shfl_xor(p, 4, 64);
        p += __shfl_xor(p, 8, 64);
        #pragma unroll
        for (int j = 0; j < 4; ++j) {
            int e2 = it * 4 + j;
            if (e2 < DEG) sc[e2] = __shfl(p, j * 16, 64);
        }
    }

    float mx = sc[0];
    #pragma unroll
    for (int e = 1; e < DEG; ++e) mx = fmaxf(mx, sc[e]);
    float den = 0.f;
    #pragma unroll
    for (int e = 0; e < DEG; ++e) { sc[e] = __expf(sc[e] - mx); den += sc[e]; }
    float inv = 1.0f / den;

    // v phase: batch index loads then batch v gathers
    int half = lane >> 5, hl = lane & 31;
    constexpr int VIT = DEG / 2;
    int vc[VIT];
    #pragma unroll
    for (int it = 0; it < VIT; ++it) vc[it] = ixs[2 * it + half];
    uint2 vraw[VIT];
    #pragma unroll
    for (int it = 0; it < VIT; ++it)
        vraw[it] = *(const uint2*)&vh[(size_t)vc[it] * 128 + hl * 4];

    float4 a = make_float4(0.f, 0.f, 0.f, 0.f);
    #pragma unroll
    for (int it = 0; it < VIT; ++it) {
        float al = (half ? sc[2 * it + 1] : sc[2 * it]) * inv;
        float2 lo = __half22float2(*(__half2*)&vraw[it].x);
        float2 hi = __half22float2(*(__half2*)&vraw[it].y);
        a.x += al * lo.x; a.y += al * lo.y; a.z += al * hi.x; a.w += al * hi.y;
    }
    a.x += __shfl_xor(a.x, 32, 64);
    a.y += __shfl_xor(a.y, 32, 64);
    a.z += __shfl_xor(a.z, 32, 64);
    a.w += __shfl_xor(a.w, 32, 64);
    if (half == 0) store_h4(&out[hl * 4], a);
}

// dual-scale attention: wave -> (node, scale); both scales in one dispatch
template<int DEG0, int DEG1>
__global__ __launch_bounds__(512)
void attn_dual_kernel(const __half* __restrict__ qh0, const __half* __restrict__ kh0,
                      const __half* __restrict__ vh0,
                      const __half* __restrict__ qh1, const __half* __restrict__ kh1,
                      const __half* __restrict__ vh1,
                      const int* __restrict__ ip0, const int* __restrict__ ix0,
                      const int* __restrict__ ip1, const int* __restrict__ ix1,
                      __half* __restrict__ aggh, int n) {
    int wid = threadIdx.x >> 6;
    int lane = threadIdx.x & 63;
    long item = (long)blockIdx.x * 8 + wid;
    if (item >= 2L * n) return;
    int node = (int)(item >> 1);
    int scale = (int)(item & 1);
    if (scale == 0) {
        int st = ip0[node];
        attn_one<DEG0>(qh0, kh0, vh0, ix0 + st,
                       aggh + (size_t)node * 256, node, lane);
    } else {
        int st = ip1[node];
        attn_one<DEG1>(qh1, kh1, vh1, ix1 + st,
                       aggh + (size_t)node * 256 + 128, node, lane);
    }
}

// per-scale fallback (uniform degree)
template<int DEG>
__global__ void attn_kernel_t(const __half* __restrict__ qh,
                              const __half* __restrict__ kh,
                              const __half* __restrict__ vh,
                              const int* __restrict__ indptr,
                              const int* __restrict__ indices,
                              __half* __restrict__ aggh, int scale, int n) {
    int wid = threadIdx.x >> 6;
    int lane = threadIdx.x & 63;
    int i = blockIdx.x * (blockDim.x >> 6) + wid;
    if (i >= n) return;
    int st = indptr[i];
    attn_one<DEG>(qh, kh, vh, indices + st,
                  aggh + (size_t)i * 256 + scale * 128, i, lane);
}

// generic fallback (any degree up to 32)
__global__ void attn_generic(const __half* __restrict__ qh,
                             const __half* __restrict__ kh,
                             const __half* __restrict__ vh,
                             const int* __restrict__ indptr,
                             const int* __restrict__ indices,
                             __half* __restrict__ aggh, int scale, int n) {
    int wid = threadIdx.x >> 6;
    int lane = threadIdx.x & 63;
    int i = blockIdx.x * (blockDim.x >> 6) + wid;
    if (i >= n) return;
    int g = lane >> 4, sl = lane & 15;
    int st = indptr[i];
    int deg = indptr[i + 1] - st;
    if (deg > 32) deg = 32;
    if (deg <= 0) {
        if (lane < 32)
            store_h4(&aggh[(size_t)i * 256 + scale * 128 + (lane & 31) * 4],
                     make_float4(0.f, 0.f, 0.f, 0.f));
        return;
    }
    float4 q = load_h4(&qh[(size_t)i * 64 + sl * 4]);
    float sc[32];
    for (int e0 = 0; e0 < deg; e0 += 4) {
        int e = e0 + g;
        int ee = (e < deg) ? e : (deg - 1);
        int c = indices[st + ee];
        float4 k = load_h4(&kh[(size_t)c * 64 + sl * 4]);
        float p = q.x * k.x + q.y * k.y + q.z * k.z + q.w * k.w;
        p += __shfl_xor(p, 1, 64);
        p += __shfl_xor(p, 2, 64);
        p += __shfl_xor(p, 4, 64);
        p += __shfl_xor(p, 8, 64);
        for (int j = 0; j < 4; ++j)
            if (e0 + j < deg) sc[e0 + j] = __shfl(p, j * 16, 64);
    }
    float mx = -INFINITY;
    for (int e = 0; e < deg; ++e) mx = fmaxf(mx, sc[e]);
    float den = 0.f;
    for (int e = 0; e < deg; ++e) { sc[e] = __expf(sc[e] - mx); den += sc[e]; }
    float inv = 1.0f / den;
    int half = lane >> 5, hl = lane & 31;
    float4 a = make_float4(0.f, 0.f, 0.f, 0.f);
    for (int e0 = 0; e0 < deg; e0 += 2) {
        int e = e0 + half;
        if (e < deg) {
            int c = indices[st + e];
            float al = sc[e] * inv;
            float4 v = load_h4(&vh[(size_t)c * 128 + hl * 4]);
            a.x += al * v.x; a.y += al * v.y; a.z += al * v.z; a.w += al * v.w;
        }
    }
    a.x += __shfl_xor(a.x, 32, 64);
    a.y += __shfl_xor(a.y, 32, 64);
    a.z += __shfl_xor(a.z, 32, 64);
    a.w += __shfl_xor(a.w, 32, 64);
    if (half == 0)
        store_h4(&aggh[(size_t)i * 256 + scale * 128 + hl * 4], a);
}

// ---------------- Wo MFMA: x += gelu(agg @ Wo + bo), D^T layout ---------------
__global__ __launch_bounds__(256)
void wo_mfma_kernel(const __half* __restrict__ aggh,   // [N,256]
                    const __half* __restrict__ Wot,    // [128,256] = Wo^T
                    const float* __restrict__ bo,      // [128]
                    float* __restrict__ x,             // [N,128] residual io
                    __half* __restrict__ xh,           // [N,128] fp16 copy
                    int n) {
    __shared__ __half As[64 * 256];                    // 32 KB, XOR-swizzled
    int t = threadIdx.x;
    int lane = t & 63, w = t >> 6;
    int m0 = blockIdx.x * 64;

    #pragma unroll
    for (int it = 0; it < 8; ++it) {
        int idx = t + it * 256;
        int row = idx >> 5, slot = idx & 31;
        int sw = slot ^ (row & 7);
        f16x8 v = f16x8_zero();
        if (m0 + row < n)
            v = *(const f16x8*)&aggh[(size_t)(m0 + row) * 256 + slot * 8];
        *(f16x8*)&As[row * 256 + sw * 8] = v;
    }
    __syncthreads();

    int lr = lane & 15, lq = lane >> 4;
    f32x4 acc[4][2];
    #pragma unroll
    for (int nf = 0; nf < 4; ++nf)
        #pragma unroll
        for (int of = 0; of < 2; ++of) {
            f32x4 z = {0.f, 0.f, 0.f, 0.f};
            acc[nf][of] = z;
        }

    const __half* Wbase = Wot + (size_t)(w * 32) * 256;
    #pragma unroll
    for (int ts = 0; ts < 8; ++ts) {
        int koct = ts * 4 + lq;
        f16x8 wf[2], af[4];
        #pragma unroll
        for (int of = 0; of < 2; ++of)
            wf[of] = *(const f16x8*)&Wbase[(size_t)(of * 16 + lr) * 256 + koct * 8];
        #pragma unroll
        for (int nf = 0; nf < 4; ++nf) {
            int row = nf * 16 + lr;
            int sw = koct ^ (row & 7);
            af[nf] = *(const f16x8*)&As[row * 256 + sw * 8];
        }
        #pragma unroll
        for (int nf = 0; nf < 4; ++nf)
            #pragma unroll
            for (int of = 0; of < 2; ++of)
                acc[nf][of] = __builtin_amdgcn_mfma_f32_16x16x32_f16(
                    wf[of], af[nf], acc[nf][of], 0, 0, 0);
    }

    #pragma unroll
    for (int nf = 0; nf < 4; ++nf) {
        int node = m0 + nf * 16 + lr;
        if (node >= n) continue;
        #pragma unroll
        for (int of = 0; of < 2; ++of) {
            int oc = w * 32 + of * 16 + lq * 4;
            float4 b = *(const float4*)&bo[oc];
            float4 xv = *(const float4*)&x[(size_t)node * 128 + oc];
            float4 r;
            r.x = xv.x + gelu_tanh(acc[nf][of][0] + b.x);
            r.y = xv.y + gelu_tanh(acc[nf][of][1] + b.y);
            r.z = xv.z + gelu_tanh(acc[nf][of][2] + b.z);
            r.w = xv.w + gelu_tanh(acc[nf][of][3] + b.w);
            *(float4*)&x[(size_t)node * 128 + oc] = r;
            store_h4(&xh[(size_t)node * 128 + oc], r);
        }
    }
}

extern "C" void kernel_launch(void* const* d_in, const int* in_sizes, int n_in,
                              void* d_out, int out_size, void* d_ws, size_t ws_size,
                              hipStream_t stream) {
    const float* coords = (const float*)d_in[0];
    const float* fields = (const float*)d_in[1];
    const int*   ip0    = (const int*)d_in[2];
    const int*   ix0    = (const int*)d_in[3];
    const int*   ip1    = (const int*)d_in[4];
    const int*   ix1    = (const int*)d_in[5];
    const float* W_in   = (const float*)d_in[6];
    const float* b_in   = (const float*)d_in[7];
    const float* Wq     = (const float*)d_in[8];
    const float* Wk     = (const float*)d_in[9];
    const float* Wv     = (const float*)d_in[10];
    const float* Wo     = (const float*)d_in[11];
    const float* bo     = (const float*)d_in[12];

    int n = in_sizes[0] / 2;          // coords is [N,2]
    float* x = (float*)d_out;         // x lives in d_out throughout

    char* ws = (char*)d_ws;
    size_t off = 0;
    auto carve = [&](size_t bytes) {
        void* p = ws + off;
        off = (off + bytes + 255) & ~(size_t)255;
        return p;
    };
    __half* xh   = (__half*)carve((size_t)n * 128 * 2);
    __half* qh0  = (__half*)carve((size_t)n * 64 * 2);
    __half* kh0  = (__half*)carve((size_t)n * 64 * 2);
    __half* vh0  = (__half*)carve((size_t)n * 128 * 2);
    __half* qh1  = (__half*)carve((size_t)n * 64 * 2);
    __half* kh1  = (__half*)carve((size_t)n * 64 * 2);
    __half* vh1  = (__half*)carve((size_t)n * 128 * 2);
    __half* aggh = (__half*)carve((size_t)n * 256 * 2);
    __half* Wt   = (__half*)carve((size_t)6 * 256 * 128 * 2);
    __half* Wot  = (__half*)carve((size_t)3 * 128 * 256 * 2);

    convert_wqkv_kernel<<<(6 * 256 * 32 + 255) / 256, 256, 0, stream>>>(Wq, Wk, Wv, Wt);
    convert_wo_kernel<<<(3 * 128 * 64 + 255) / 256, 256, 0, stream>>>(Wo, Wot);

    geom_prologue_kernel<<<(n + 1) / 2, 256, 0, stream>>>(coords, fields, ip0, ix0,
                                                          ip1, ix1, W_in, b_in,
                                                          x, xh, n);

    int deg0 = in_sizes[3] / n;
    int deg1 = in_sizes[5] / n;
    bool uni0 = (deg0 * n == in_sizes[3]);
    bool uni1 = (deg1 * n == in_sizes[5]);

    auto launch_attn_single = [&](int deg, bool uni, const int* ip, const int* ix,
                                  const __half* qh, const __half* kh, const __half* vh,
                                  int scale) {
        int ab = (n + 3) / 4;
        if (uni) {
            switch (deg) {
                case 4:  attn_kernel_t<4><<<ab, 256, 0, stream>>>(qh, kh, vh, ip, ix, aggh, scale, n); return;
                case 6:  attn_kernel_t<6><<<ab, 256, 0, stream>>>(qh, kh, vh, ip, ix, aggh, scale, n); return;
                case 8:  attn_kernel_t<8><<<ab, 256, 0, stream>>>(qh, kh, vh, ip, ix, aggh, scale, n); return;
                case 12: attn_kernel_t<12><<<ab, 256, 0, stream>>>(qh, kh, vh, ip, ix, aggh, scale, n); return;
                case 16: attn_kernel_t<16><<<ab, 256, 0, stream>>>(qh, kh, vh, ip, ix, aggh, scale, n); return;
            }
        }
        attn_generic<<<ab, 256, 0, stream>>>(qh, kh, vh, ip, ix, aggh, scale, n);
    };

    bool dual_ok = uni0 && uni1 && deg0 == 12 && deg1 == 4;
    int dual_blocks = (int)((2L * n + 7) / 8);
    int gblocks = (n + 63) / 64;

    for (int l = 0; l < 3; ++l) {
        const __half* WtL = Wt + (size_t)(l * 2) * 256 * 128;
        qkv_dual_mfma_kernel<<<gblocks, 512, 0, stream>>>(xh, WtL, qh0, kh0, vh0,
                                                          qh1, kh1, vh1, n);
        if (dual_ok) {
            attn_dual_kernel<12, 4><<<dual_blocks, 512, 0, stream>>>(
                qh0, kh0, vh0, qh1, kh1, vh1, ip0, ix0, ip1, ix1, aggh, n);
        } else {
            launch_attn_single(deg0, uni0, ip0, ix0, qh0, kh0, vh0, 0);
            launch_attn_single(deg1, uni1, ip1, ix1, qh1, kh1, vh1, 1);
        }
        wo_mfma_kernel<<<gblocks, 256, 0, stream>>>(aggh, Wot + (size_t)l * 128 * 256,
                                                    bo + l * 128, x, xh, n);
    }
}